// Round 19
// baseline (5975.206 us; speedup 1.0000x reference)
//
#include <hip/hip_runtime.h>

typedef short short8 __attribute__((ext_vector_type(8)));
typedef float f32x4  __attribute__((ext_vector_type(4)));
typedef unsigned long long u64;

#define NSTEP 515
#define NDISP 258        // ceil(516/2): w = 2j, 2j+1; w=515 auto-inactive
#define NWG 96
#define NGRP 8
#define GSZ  12

// ---- workspace layout (bytes) ----
#define OFF_WH1  0ull              // packed Whh1 frags (kb-major): 32 ug * 64KB = 2MB
#define OFF_WH2  2097152ull
#define OFF_WH3  4194304ull
#define OFF_WI2  6291456ull
#define OFF_WI3  8388608ull
#define OFF_V1   10485760ull       // v1[2048] f32
#define OFF_U1   10493952ull       // u1[2048] f32
#define OFF_B2   10502144ull       // bias2[2048] f32
#define OFF_B3   10510336ull       // bias3[2048] f32
#define OFF_XT   10518528ull       // xT[512][128] f32 (256KB)
#define OFF_HR   10780672ull       // h rings: [3 layer][2 slot][16 kb][8 mb][512] u16 = 768KB
#define OFF_P3   11567104ull       // part3: [3 slot][32][128] f32 = 48KB
#define OFF_C    11616256ull       // cell state: [3][128][512] f32 = 768KB
#define OFF_BAR  12402688ull       // barrier block (4KB)

__device__ __forceinline__ unsigned short bf16rne(float f) {
    unsigned u = __float_as_uint(f);
    return (unsigned short)((u + 0x7FFFu + ((u >> 16) & 1u)) >> 16);
}

__device__ __forceinline__ float sigm(float x) { return 1.0f / (1.0f + expf(-x)); }

// Coherent loads (sc0 sc1, bypass stale L2) — batched, then ONE vm_drain.
__device__ __forceinline__ short8 cload16(const void* p) {
    short8 r;
    asm volatile("global_load_dwordx4 %0, %1, off sc0 sc1" : "=v"(r) : "v"(p));
    return r;
}
__device__ __forceinline__ float cload4(const void* p) {
    float r;
    asm volatile("global_load_dword %0, %1, off sc0 sc1" : "=v"(r) : "v"(p));
    return r;
}
__device__ __forceinline__ void vm_drain() {
    asm volatile("s_waitcnt vmcnt(0)" ::: "memory");
    __builtin_amdgcn_sched_barrier(0);
}

__global__ void fill_sentinel(float* __restrict__ out)
{
    int e = blockIdx.x * 256 + threadIdx.x;
    if (e < 65536) out[e] = 0.75f;
}

// Zero h rings + part3 + cell state (1584KB contiguous).
__global__ void zero_state(char* __restrict__ ws)
{
    int e = blockIdx.x * 256 + threadIdx.x;
    float4 z = {0.f, 0.f, 0.f, 0.f};
    if (e < 101376) *(float4*)(ws + OFF_HR + (size_t)e * 16) = z;
}

__global__ void zero_bar(char* __restrict__ ws)
{
    ((unsigned*)(ws + OFF_BAR))[threadIdx.x] = 0u;    // 1024 thr clear 4KB
}

// Pack one 2048x512 gate matrix into MFMA B-fragments, kb-major.
__global__ void pack_w(const float* __restrict__ W, unsigned short* __restrict__ dst)
{
    int e = blockIdx.x * 256 + threadIdx.x;     // exactly 1,048,576
    int j    = e & 7;
    int lane = (e >> 3) & 63;
    int nb   = (e >> 9) & 3;
    int kb   = (e >> 11) & 15;
    int ug   = e >> 15;
    int row = nb * 512 + ug * 16 + (lane & 15);
    int col = kb * 32 + (lane >> 4) * 8 + j;
    dst[e] = bf16rne(W[row * 512 + col]);
}

__global__ void prep_vec(const float* __restrict__ Wih1, const float* __restrict__ W1,
                         const float* __restrict__ b1,
                         const float* __restrict__ bih1, const float* __restrict__ bhh1,
                         const float* __restrict__ bih2, const float* __restrict__ bhh2,
                         const float* __restrict__ bih3, const float* __restrict__ bhh3,
                         float* __restrict__ v1, float* __restrict__ u1,
                         float* __restrict__ bias2, float* __restrict__ bias3)
{
    int r = blockIdx.x * 256 + threadIdx.x;
    if (r >= 2048) return;
    float sv = 0.f, su = 0.f;
    for (int k = 0; k < 512; ++k) {
        float w = Wih1[r * 512 + k];
        sv += w * W1[k];
        su += w * b1[k];
    }
    v1[r] = sv;
    u1[r] = su + bih1[r] + bhh1[r];
    bias2[r] = bih2[r] + bhh2[r];
    bias3[r] = bih3[r] + bhh3[r];
}

__global__ void prep_xt(const float* __restrict__ x, float* __restrict__ xT)
{
    int e = blockIdx.x * 256 + threadIdx.x;
    if (e >= 65536) return;
    int b = e >> 9, t = e & 511;
    xT[t * 128 + b] = x[e];
}

// ---- hierarchical split-phase barrier (measured ~1.7us @96 wgs) ----
__device__ __forceinline__ void gbar_arrive(unsigned* bar, int wg, unsigned s)
{
    __syncthreads();                  // drains vmcnt: WT stores at coherence point
    if (threadIdx.x == 0) {
        unsigned g = (unsigned)wg & 7u;
        unsigned old = atomicAdd(bar + 64 + g * 32, 1u);
        if (old == s * GSZ - 1) {
            unsigned ro = atomicAdd(bar, 1u);
            if (ro == s * NGRP - 1)
                __hip_atomic_store(bar + 32, s, __ATOMIC_RELAXED,
                                   __HIP_MEMORY_SCOPE_AGENT);
        }
    }
}
__device__ __forceinline__ void gbar_wait(unsigned* bar, unsigned s)
{
    if (threadIdx.x == 0) {
        while (__hip_atomic_load(bar + 32, __ATOMIC_RELAXED,
                                 __HIP_MEMORY_SCOPE_AGENT) < s)
            __builtin_amdgcn_s_sleep(1);
    }
    __syncthreads();
}

// Double-buffered B-chunk GEMM (R18, unchanged). NM mats x 4 chunks of 16KB.
template<int NM>
__device__ __forceinline__ void gemm_chunks(
    const unsigned short* __restrict__ wsrc0,
    const unsigned short* __restrict__ wsrc1,
    const short8 (&A)[NM][16],
    unsigned short (&bsh)[2][8192],
    int tid, int lane, f32x4 (&acc)[4])
{
    const unsigned short* wsrc[2] = { wsrc0, wsrc1 };
    short8 r0, r1;
    r0 = *(const short8*)(wsrc[0] + tid * 8);
    r1 = *(const short8*)(wsrc[0] + 4096 + tid * 8);
    *(short8*)(&bsh[0][tid * 8]) = r0;
    *(short8*)(&bsh[0][4096 + tid * 8]) = r1;
    __syncthreads();
    #pragma unroll
    for (int cc = 0; cc < 4 * NM; ++cc) {
        const int m = cc >> 2;
        const int nm_ = cc + 1;
        if (nm_ < 4 * NM) {
            const unsigned short* src = wsrc[nm_ >> 2] + (nm_ & 3) * 8192;
            r0 = *(const short8*)(src + tid * 8);
            r1 = *(const short8*)(src + 4096 + tid * 8);
        }
        #pragma unroll
        for (int k2 = 0; k2 < 4; ++k2) {
            const int kb = (cc & 3) * 4 + k2;
            #pragma unroll
            for (int nb = 0; nb < 4; ++nb) {
                short8 bw = *(const short8*)(&bsh[cc & 1][(k2 * 4 + nb) * 512 + lane * 8]);
                acc[nb] = __builtin_amdgcn_mfma_f32_16x16x32_bf16(A[m][kb], bw, acc[nb], 0, 0, 0);
            }
        }
        if (nm_ < 4 * NM) {
            *(short8*)(&bsh[nm_ & 1][tid * 8]) = r0;
            *(short8*)(&bsh[nm_ & 1][4096 + tid * 8]) = r1;
        }
        __syncthreads();
    }
}

template<int COH>
__device__ __forceinline__ void load_A16(short8 (&A)[16], const unsigned short* h,
                                         int wv, int lane)
{
    #pragma unroll
    for (int kb = 0; kb < 16; ++kb) {
        const void* p = h + ((kb * 8 + wv) * 512) + lane * 8;
        if constexpr (COH) A[kb] = cload16(p);
        else               A[kb] = *(const short8*)p;
    }
}

// One LSTM step body. INC: coherent A-loads. OUTC: write-through publishes.
template<int INC, int OUTC>
__device__ __forceinline__ void lstm_body(
    char* __restrict__ ws, unsigned short* __restrict__ hr, float* __restrict__ part3,
    const float* __restrict__ xT, int w, int layer, int ug,
    int tid, int lane, int wv, int q, int l15, int gu,
    const float (&cv)[4], const float (&cu_)[4], float w2v,
    float (&c_st)[4],
    unsigned short (&bsh)[2][8192], unsigned short (&stage)[8][16][16])
{
    const int cur = w & 1, prev = cur ^ 1;
    const int t = w - layer;
    if (t < 0 || t >= 512) return;          // uniform per wg

    f32x4 acc[4] = {};
    if (layer == 0) {
        short8 A[1][16];
        load_A16<INC>(A[0], hr + (size_t)prev * 65536, wv, lane);
        if constexpr (INC) vm_drain();
        gemm_chunks<1>((const unsigned short*)(ws + OFF_WH1) + (size_t)ug * 32768,
                       nullptr, A, bsh, tid, lane, acc);
    } else {
        short8 A[2][16];
        load_A16<INC>(A[0], hr + (size_t)((layer - 1) * 2 + prev) * 65536, wv, lane);
        load_A16<INC>(A[1], hr + (size_t)(layer * 2 + prev) * 65536, wv, lane);
        if constexpr (INC) vm_drain();
        gemm_chunks<2>((const unsigned short*)(ws + ((layer == 1) ? OFF_WI2 : OFF_WI3)) + (size_t)ug * 32768,
                       (const unsigned short*)(ws + ((layer == 1) ? OFF_WH2 : OFF_WH3)) + (size_t)ug * 32768,
                       A, bsh, tid, lane, acc);
    }

    // epilogue: gates in-lane (unit gu), batch b = wv*16 + q*4 + rr
    #pragma unroll
    for (int rr = 0; rr < 4; ++rr) {
        const int b = wv * 16 + q * 4 + rr;
        const float xv = (layer == 0) ? xT[t * 128 + b] : 1.0f;
        float gi = acc[0][rr] + xv * cv[0] + cu_[0];
        float gf = acc[1][rr] + xv * cv[1] + cu_[1];
        float gg = acc[2][rr] + xv * cv[2] + cu_[2];
        float go = acc[3][rr] + xv * cv[3] + cu_[3];
        float c = sigm(gf) * c_st[rr] + sigm(gi) * tanhf(gg);
        c_st[rr] = c;
        float h = sigm(go) * tanhf(c);
        stage[wv][q * 4 + rr][l15] = bf16rne(h);
        if (layer == 2) {
            float v = h * w2v;                  // partial of out[b][t]
            v += __shfl_xor(v, 1); v += __shfl_xor(v, 2);
            v += __shfl_xor(v, 4); v += __shfl_xor(v, 8);
            if (l15 == 0) {
                float* p = &part3[((size_t)(w % 3) * 32 + ug) * 128 + b];
                if constexpr (OUTC)
                    __hip_atomic_store(p, v, __ATOMIC_RELAXED, __HIP_MEMORY_SCOPE_AGENT);
                else
                    *p = v;
            }
        }
    }
    // publish h fragment
    {
        u64* dst64 = (u64*)(hr + (size_t)(layer * 2 + cur) * 65536
                               + ((size_t)(ug >> 1) * 8 + wv) * 512);
        const int row = lane >> 2, q4 = lane & 3;
        u64 v = *(const u64*)&stage[wv][row][q4 * 4];
        const int idx = (((ug & 1) * 2 + (q4 >> 1)) * 16 + row) * 2 + (q4 & 1);
        if constexpr (OUTC)
            __hip_atomic_store(dst64 + idx, v, __ATOMIC_RELAXED, __HIP_MEMORY_SCOPE_AGENT);
        else
            dst64[idx] = v;
    }
}

// Two skewed steps per dispatch: phase A (w=2j, plain-in/WT-out), internal
// barrier, phase B (w=2j+1, coherent-in/plain-out). Weights L2-hot in phase B.
// wg 96: out-projection (phase A plain, phase B batched-coherent); polls only.
__global__ void __launch_bounds__(512)
step2_k(char* __restrict__ ws, const float* __restrict__ W2,
        const float* __restrict__ b2, float* __restrict__ out, int j)
{
    __shared__ __align__(16) unsigned short bsh[2][8192];
    __shared__ __align__(16) unsigned short stage[8][16][16];

    const int tid = threadIdx.x, lane = tid & 63, wv = tid >> 6;
    const int q = lane >> 4, l15 = lane & 15;
    const int wg = blockIdx.x;
    const int wA = 2 * j, wB = 2 * j + 1;
    const unsigned s = (unsigned)j + 1;

    unsigned short* hr = (unsigned short*)(ws + OFF_HR);
    float* part3 = (float*)(ws + OFF_P3);
    unsigned* bar = (unsigned*)(ws + OFF_BAR);

    if (wg == 96) {
        if (wA >= 3 && tid < 128) {                         // t = wA-3 (plain)
            const float* p = part3 + (size_t)((wA - 1) % 3) * 32 * 128;
            float v = 0.f;
            #pragma unroll
            for (int i = 0; i < 32; ++i) v += p[i * 128 + tid];
            out[(size_t)tid * 512 + (wA - 3)] = v + b2[0];
        }
        gbar_wait(bar, s);                                  // poll only
        if (wB >= 3 && wB < 515 && tid < 128) {             // t = wB-3 (coherent)
            const float* p = part3 + (size_t)((wB - 1) % 3) * 32 * 128;
            float vv[32];
            #pragma unroll
            for (int i = 0; i < 32; ++i) vv[i] = cload4(p + i * 128 + tid);
            vm_drain();
            float v = 0.f;
            #pragma unroll
            for (int i = 0; i < 32; ++i) v += vv[i];
            out[(size_t)tid * 512 + (wB - 3)] = v + b2[0];
        }
        return;
    }

    const int layer = wg >> 5, ug = wg & 31;
    const int gu = ug * 16 + l15;
    const float* xT = (const float*)(ws + OFF_XT);
    float* C = (float*)(ws + OFF_C);

    float cv[4], cu_[4];
    if (layer == 0) {
        const float* v1 = (const float*)(ws + OFF_V1);
        const float* u1 = (const float*)(ws + OFF_U1);
        #pragma unroll
        for (int g = 0; g < 4; ++g) { cv[g] = v1[g * 512 + gu]; cu_[g] = u1[g * 512 + gu]; }
    } else {
        const float* bs = (const float*)(ws + ((layer == 1) ? OFF_B2 : OFF_B3));
        #pragma unroll
        for (int g = 0; g < 4; ++g) { cv[g] = bs[g * 512 + gu]; cu_[g] = 0.f; }
    }
    const float w2v = (layer == 2) ? W2[gu] : 0.f;

    float c_st[4];
    #pragma unroll
    for (int rr = 0; rr < 4; ++rr) {
        const int b = wv * 16 + q * 4 + rr;
        c_st[rr] = C[((size_t)layer * 128 + b) * 512 + gu];
    }

    lstm_body<0, 1>(ws, hr, part3, xT, wA, layer, ug, tid, lane, wv, q, l15, gu,
                    cv, cu_, w2v, c_st, bsh, stage);
    gbar_arrive(bar, wg, s);
    gbar_wait(bar, s);
    lstm_body<1, 0>(ws, hr, part3, xT, wB, layer, ug, tid, lane, wv, q, l15, gu,
                    cv, cu_, w2v, c_st, bsh, stage);

    #pragma unroll
    for (int rr = 0; rr < 4; ++rr) {
        const int b = wv * 16 + q * 4 + rr;
        C[((size_t)layer * 128 + b) * 512 + gu] = c_st[rr];
    }
}

// Kept to match the harness-provided template symbol (unused).
__global__ void Sequence_85564338471528_kernel() {}

extern "C" void kernel_launch(void* const* d_in, const int* in_sizes, int n_in,
                              void* d_out, int out_size, void* d_ws, size_t ws_size,
                              hipStream_t stream)
{
    const float* x    = (const float*)d_in[0];
    const float* W1   = (const float*)d_in[2];
    const float* b1   = (const float*)d_in[3];
    const float* W2   = (const float*)d_in[4];
    const float* b2   = (const float*)d_in[5];
    const float* Wih1 = (const float*)d_in[6];
    const float* Whh1 = (const float*)d_in[7];
    const float* bih1 = (const float*)d_in[8];
    const float* bhh1 = (const float*)d_in[9];
    const float* Wih2 = (const float*)d_in[10];
    const float* Whh2 = (const float*)d_in[11];
    const float* bih2 = (const float*)d_in[12];
    const float* bhh2 = (const float*)d_in[13];
    const float* Wih3 = (const float*)d_in[14];
    const float* Whh3 = (const float*)d_in[15];
    const float* bih3 = (const float*)d_in[16];
    const float* bhh3 = (const float*)d_in[17];
    char* ws = (char*)d_ws;
    float* out = (float*)d_out;

    fill_sentinel<<<256, 256, 0, stream>>>(out);
    zero_state<<<396, 256, 0, stream>>>(ws);
    zero_bar<<<1, 1024, 0, stream>>>(ws);

    pack_w<<<4096, 256, 0, stream>>>(Whh1, (unsigned short*)(ws + OFF_WH1));
    pack_w<<<4096, 256, 0, stream>>>(Whh2, (unsigned short*)(ws + OFF_WH2));
    pack_w<<<4096, 256, 0, stream>>>(Whh3, (unsigned short*)(ws + OFF_WH3));
    pack_w<<<4096, 256, 0, stream>>>(Wih2, (unsigned short*)(ws + OFF_WI2));
    pack_w<<<4096, 256, 0, stream>>>(Wih3, (unsigned short*)(ws + OFF_WI3));
    prep_vec<<<8, 256, 0, stream>>>(Wih1, W1, b1, bih1, bhh1, bih2, bhh2, bih3, bhh3,
                                    (float*)(ws + OFF_V1), (float*)(ws + OFF_U1),
                                    (float*)(ws + OFF_B2), (float*)(ws + OFF_B3));
    prep_xt<<<256, 256, 0, stream>>>(x, (float*)(ws + OFF_XT));

    for (int j = 0; j < NDISP; ++j)
        step2_k<<<97, 512, 0, stream>>>(ws, W2, b2, out, j);
}

// Round 20
// 4879.610 us; speedup vs baseline: 1.2245x; 1.2245x over previous
//
#include <hip/hip_runtime.h>

typedef short short8 __attribute__((ext_vector_type(8)));
typedef float f32x4  __attribute__((ext_vector_type(4)));
typedef unsigned long long u64;

#define NSTEP 515

// ---- workspace layout (bytes) ----
#define OFF_WH1  0ull              // packed Whh1 frags (kb-major): 32 ug * 64KB = 2MB
#define OFF_WH2  2097152ull
#define OFF_WH3  4194304ull
#define OFF_WI2  6291456ull
#define OFF_WI3  8388608ull
#define OFF_V1   10485760ull       // v1[2048] f32
#define OFF_U1   10493952ull       // u1[2048] f32
#define OFF_B2   10502144ull       // bias2[2048] f32
#define OFF_B3   10510336ull       // bias3[2048] f32
#define OFF_XT   10518528ull       // xT[512][128] f32 (256KB)
#define OFF_HR   10780672ull       // h rings: [3 layer][2 slot][16 kb][8 mb][512] u16 = 768KB
#define OFF_P3   11567104ull       // part3: [3 slot][32][128] f32 = 48KB
#define OFF_C    11616256ull       // cell state: [3][128][512] f32 = 768KB

__device__ __forceinline__ unsigned short bf16rne(float f) {
    unsigned u = __float_as_uint(f);
    return (unsigned short)((u + 0x7FFFu + ((u >> 16) & 1u)) >> 16);
}

__device__ __forceinline__ float sigm(float x) { return 1.0f / (1.0f + expf(-x)); }

// Sentinel: 0.0508 absmax -> nothing ran; ~0.75 -> step_k broken; ~2e-4 -> PASS.
__global__ void fill_sentinel(float* __restrict__ out)
{
    int e = blockIdx.x * 256 + threadIdx.x;
    if (e < 65536) out[e] = 0.75f;
}

// Zero h rings + part3 + cell state (1584KB contiguous).
__global__ void zero_state(char* __restrict__ ws)
{
    int e = blockIdx.x * 256 + threadIdx.x;
    float4 z = {0.f, 0.f, 0.f, 0.f};
    if (e < 101376) *(float4*)(ws + OFF_HR + (size_t)e * 16) = z;
}

// Pack one 2048x512 gate matrix into MFMA B-fragments, kb-major:
// e = (((ug*16 + kb)*4 + nb)*64 + lane)*8 + j
// value = W[nb*512 + ug*16 + (lane&15)][kb*32 + (lane>>4)*8 + j]
__global__ void pack_w(const float* __restrict__ W, unsigned short* __restrict__ dst)
{
    int e = blockIdx.x * 256 + threadIdx.x;     // exactly 1,048,576
    int j    = e & 7;
    int lane = (e >> 3) & 63;
    int nb   = (e >> 9) & 3;
    int kb   = (e >> 11) & 15;
    int ug   = e >> 15;
    int row = nb * 512 + ug * 16 + (lane & 15);
    int col = kb * 32 + (lane >> 4) * 8 + j;
    dst[e] = bf16rne(W[row * 512 + col]);
}

// v1 = Wih1 @ W1[:,0]; u1 = Wih1 @ b1 + bih1 + bhh1; bias2/3 = bih+bhh
__global__ void prep_vec(const float* __restrict__ Wih1, const float* __restrict__ W1,
                         const float* __restrict__ b1,
                         const float* __restrict__ bih1, const float* __restrict__ bhh1,
                         const float* __restrict__ bih2, const float* __restrict__ bhh2,
                         const float* __restrict__ bih3, const float* __restrict__ bhh3,
                         float* __restrict__ v1, float* __restrict__ u1,
                         float* __restrict__ bias2, float* __restrict__ bias3)
{
    int r = blockIdx.x * 256 + threadIdx.x;
    if (r >= 2048) return;
    float sv = 0.f, su = 0.f;
    for (int k = 0; k < 512; ++k) {
        float w = Wih1[r * 512 + k];
        sv += w * W1[k];
        su += w * b1[k];
    }
    v1[r] = sv;
    u1[r] = su + bih1[r] + bhh1[r];
    bias2[r] = bih2[r] + bhh2[r];
    bias3[r] = bih3[r] + bhh3[r];
}

__global__ void prep_xt(const float* __restrict__ x, float* __restrict__ xT)
{
    int e = blockIdx.x * 256 + threadIdx.x;
    if (e >= 65536) return;
    int b = e >> 9, t = e & 511;
    xT[t * 128 + b] = x[e];
}

// Full-mat upfront staged GEMM. Per mat: stage 64KB B slice into LDS in one
// burst (16 x 16B per thread, grouped 8+8 -> 2 exposed latencies), sync, then
// 64 MFMAs consume from LDS uninterrupted. acc accumulates across mats.
template<int NM>
__device__ __forceinline__ void gemm_full(
    const unsigned short* __restrict__ wsrc0,
    const unsigned short* __restrict__ wsrc1,
    const short8 (&A)[NM][16],
    unsigned short* __restrict__ bsh,
    int tid, int lane, f32x4 (&acc)[4])
{
    const unsigned short* ws2[2] = { wsrc0, wsrc1 };
    #pragma unroll
    for (int m = 0; m < NM; ++m) {
        if (m) __syncthreads();                 // prior mat fully consumed
        short8 br[8];
        #pragma unroll
        for (int g = 0; g < 2; ++g) {
            #pragma unroll
            for (int i = 0; i < 8; ++i)
                br[i] = *(const short8*)(ws2[m] + (g * 8 + i) * 2048 + tid * 8);
            #pragma unroll
            for (int i = 0; i < 8; ++i)
                *(short8*)(bsh + (g * 8 + i) * 2048 + tid * 8) = br[i];
        }
        __syncthreads();                        // staging visible
        #pragma unroll
        for (int kb = 0; kb < 16; ++kb) {
            #pragma unroll
            for (int nb = 0; nb < 4; ++nb) {
                short8 bw = *(const short8*)(bsh + (kb * 4 + nb) * 512 + lane * 8);
                acc[nb] = __builtin_amdgcn_mfma_f32_16x16x32_bf16(A[m][kb], bw, acc[nb], 0, 0, 0);
            }
        }
    }
}

// One skewed step; kernel boundary = global sync.
// wg < 192: bh = wg/96 (batch half), lw = wg%96, layer = lw>>5, ug = lw&31.
//   (bh-siblings differ by 96 = 0 mod 8 -> same XCD -> B lines shared via L2.)
//   256 thr = 4 waves; wave wv owns mblk = bh*4 + wv (16 batches).
// wg 192: out-projection reduce for t_o = w-3.
__global__ void __launch_bounds__(256)
step_k(char* __restrict__ ws, const float* __restrict__ W2,
       const float* __restrict__ b2, float* __restrict__ out, int w)
{
    extern __shared__ char ldsraw[];                       // 64KB: one B mat
    unsigned short* bsh = (unsigned short*)ldsraw;

    const int cur = w & 1, prev = cur ^ 1;
    const int tid = threadIdx.x, lane = tid & 63, wv = tid >> 6;
    const int q = lane >> 4, l15 = lane & 15;
    const int wg = blockIdx.x;

    unsigned short* hr = (unsigned short*)(ws + OFF_HR);
    float* part3 = (float*)(ws + OFF_P3);

    if (wg == 192) {                                       // out[b][w-3]
        if (w < 3 || tid >= 128) return;
        const int b = tid;
        const float* p = part3 + (size_t)((w - 1) % 3) * 32 * 128;
        float v = 0.f;
        #pragma unroll
        for (int i = 0; i < 32; ++i) v += p[i * 128 + b];
        out[(size_t)b * 512 + (w - 3)] = v + b2[0];
        return;
    }

    const int bh = wg / 96, lw = wg % 96;
    const int layer = lw >> 5, ug = lw & 31;
    const int t = w - layer;
    if (t < 0 || t >= 512) return;
    const int gu = ug * 16 + l15;
    const int mblk = bh * 4 + wv;

    float cv[4], cu_[4];
    if (layer == 0) {
        const float* v1 = (const float*)(ws + OFF_V1);
        const float* u1 = (const float*)(ws + OFF_U1);
        #pragma unroll
        for (int g = 0; g < 4; ++g) { cv[g] = v1[g * 512 + gu]; cu_[g] = u1[g * 512 + gu]; }
    } else {
        const float* bs = (const float*)(ws + ((layer == 1) ? OFF_B2 : OFF_B3));
        #pragma unroll
        for (int g = 0; g < 4; ++g) { cv[g] = bs[g * 512 + gu]; cu_[g] = 0.f; }
    }
    const float w2v = (layer == 2) ? W2[gu] : 0.f;
    const float* xT = (const float*)(ws + OFF_XT);
    float* C = (float*)(ws + OFF_C);

    float c_st[4];
    #pragma unroll
    for (int rr = 0; rr < 4; ++rr) {
        const int b = mblk * 16 + q * 4 + rr;
        c_st[rr] = C[((size_t)layer * 128 + b) * 512 + gu];
    }

    f32x4 acc[4] = {};
    if (layer == 0) {
        const unsigned short* hS = hr + (size_t)prev * 65536;
        short8 A[1][16];
        #pragma unroll
        for (int kb = 0; kb < 16; ++kb)
            A[0][kb] = *(const short8*)(hS + ((kb * 8 + mblk) * 512) + lane * 8);
        gemm_full<1>((const unsigned short*)(ws + OFF_WH1) + (size_t)ug * 32768,
                     nullptr, A, bsh, tid, lane, acc);
    } else {
        const unsigned short* hA0 = hr + (size_t)((layer - 1) * 2 + prev) * 65536;
        const unsigned short* hA1 = hr + (size_t)(layer * 2 + prev) * 65536;
        short8 A[2][16];
        #pragma unroll
        for (int kb = 0; kb < 16; ++kb)
            A[0][kb] = *(const short8*)(hA0 + ((kb * 8 + mblk) * 512) + lane * 8);
        #pragma unroll
        for (int kb = 0; kb < 16; ++kb)
            A[1][kb] = *(const short8*)(hA1 + ((kb * 8 + mblk) * 512) + lane * 8);
        gemm_full<2>((const unsigned short*)(ws + ((layer == 1) ? OFF_WI2 : OFF_WI3)) + (size_t)ug * 32768,
                     (const unsigned short*)(ws + ((layer == 1) ? OFF_WH2 : OFF_WH3)) + (size_t)ug * 32768,
                     A, bsh, tid, lane, acc);
    }

    // epilogue: gates in-lane (unit gu), batch b = mblk*16 + q*4 + rr.
    // h published by direct u16 scatter (no LDS stage).
    const int u5 = (ug & 1) * 16 + l15;
    unsigned short* dblk = hr + (size_t)(layer * 2 + cur) * 65536
                              + ((size_t)(ug >> 1) * 8 + mblk) * 512;
    #pragma unroll
    for (int rr = 0; rr < 4; ++rr) {
        const int b = mblk * 16 + q * 4 + rr;
        const float xv = (layer == 0) ? xT[t * 128 + b] : 1.0f;
        float gi = acc[0][rr] + xv * cv[0] + cu_[0];
        float gf = acc[1][rr] + xv * cv[1] + cu_[1];
        float gg = acc[2][rr] + xv * cv[2] + cu_[2];
        float go = acc[3][rr] + xv * cv[3] + cu_[3];
        float c = sigm(gf) * c_st[rr] + sigm(gi) * tanhf(gg);
        C[((size_t)layer * 128 + b) * 512 + gu] = c;
        float h = sigm(go) * tanhf(c);
        dblk[((u5 >> 3) * 16 + (q * 4 + rr)) * 8 + (u5 & 7)] = bf16rne(h);
        if (layer == 2) {
            float v = h * w2v;                      // partial of out[b][t]
            v += __shfl_xor(v, 1); v += __shfl_xor(v, 2);
            v += __shfl_xor(v, 4); v += __shfl_xor(v, 8);
            if (l15 == 0)
                part3[((size_t)(w % 3) * 32 + ug) * 128 + b] = v;
        }
    }
}

// Kept to match the harness-provided template symbol (unused).
__global__ void Sequence_85564338471528_kernel() {}

extern "C" void kernel_launch(void* const* d_in, const int* in_sizes, int n_in,
                              void* d_out, int out_size, void* d_ws, size_t ws_size,
                              hipStream_t stream)
{
    const float* x    = (const float*)d_in[0];
    const float* W1   = (const float*)d_in[2];
    const float* b1   = (const float*)d_in[3];
    const float* W2   = (const float*)d_in[4];
    const float* b2   = (const float*)d_in[5];
    const float* Wih1 = (const float*)d_in[6];
    const float* Whh1 = (const float*)d_in[7];
    const float* bih1 = (const float*)d_in[8];
    const float* bhh1 = (const float*)d_in[9];
    const float* Wih2 = (const float*)d_in[10];
    const float* Whh2 = (const float*)d_in[11];
    const float* bih2 = (const float*)d_in[12];
    const float* bhh2 = (const float*)d_in[13];
    const float* Wih3 = (const float*)d_in[14];
    const float* Whh3 = (const float*)d_in[15];
    const float* bih3 = (const float*)d_in[16];
    const float* bhh3 = (const float*)d_in[17];
    char* ws = (char*)d_ws;
    float* out = (float*)d_out;

    fill_sentinel<<<256, 256, 0, stream>>>(out);
    zero_state<<<396, 256, 0, stream>>>(ws);

    pack_w<<<4096, 256, 0, stream>>>(Whh1, (unsigned short*)(ws + OFF_WH1));
    pack_w<<<4096, 256, 0, stream>>>(Whh2, (unsigned short*)(ws + OFF_WH2));
    pack_w<<<4096, 256, 0, stream>>>(Whh3, (unsigned short*)(ws + OFF_WH3));
    pack_w<<<4096, 256, 0, stream>>>(Wih2, (unsigned short*)(ws + OFF_WI2));
    pack_w<<<4096, 256, 0, stream>>>(Wih3, (unsigned short*)(ws + OFF_WI3));
    prep_vec<<<8, 256, 0, stream>>>(Wih1, W1, b1, bih1, bhh1, bih2, bhh2, bih3, bhh3,
                                    (float*)(ws + OFF_V1), (float*)(ws + OFF_U1),
                                    (float*)(ws + OFF_B2), (float*)(ws + OFF_B3));
    prep_xt<<<256, 256, 0, stream>>>(x, (float*)(ws + OFF_XT));

    for (int w = 0; w < NSTEP; ++w)
        step_k<<<193, 256, 65536, stream>>>(ws, W2, b2, out, w);
}